// Round 7
// baseline (772.605 us; speedup 1.0000x reference)
//
#include <hip/hip_runtime.h>
#include <hip/hip_cooperative_groups.h>
#include <stdint.h>

namespace cg = cooperative_groups;

// ---------------------------------------------------------------------------
// Exact top-k (k=10%) magnitude mask via 16-bit-prefix radix select.
// Primary path: ONE cooperative kernel (5 grid.sync()s) -- kills the ~310us of
// stable non-mask time (suspected per-dispatch boundary overhead).
// Fallback path (if cooperative launch unsupported): the verified round-5
// six-kernel pipeline.
//
// d_out (33554432 u32 words) scratch layout:
//   [0, 131072)    : two 65536-bin histograms (zeroed ph0, filled ph1,
//                    read ph2, overwritten by matrix-0 mask in ph3)
//   [RBASE, end)   : candidate (idx,u) pairs, CCAP per matrix (matrix-1 mask
//                    skips this tail; ph5/fill_tail writes it exactly)
// d_ws (64 u32): per matrix m at ws+8*m: [0]=P [1]=rank [3]=T [4]=C;
//   candidate counters at ws[32]/ws[48] (own cache lines).
// ---------------------------------------------------------------------------

#define NBINS       65536u
#define CCAP        65536u
#define TOTAL_WORDS 33554432u
#define RWORDS      (2u * CCAP * 2u)                // 262144 words = 1 MiB
#define RBASE       (TOTAL_WORDS - RWORDS)          // 33292288
#define SKIP_WORD   (RBASE - 16777216u)             // 16515072
#define SKIP_F4     (SKIP_WORD / 4u)                // 4128768
#define CNT(m)      (32u + (uint32_t)(m) * 16u)
#define TPB         1024
#define LCAP        2048u                           // per-block staging cap
#define SMW         34824                           // 136.03 KiB LDS

typedef float floatx4 __attribute__((ext_vector_type(4)));
__device__ __forceinline__ void nt_store4(float4* p, float a, float b, float c, float d) {
  floatx4 v = {a, b, c, d};
  __builtin_nontemporal_store(v, reinterpret_cast<floatx4*>(p));
}
__device__ __forceinline__ uint32_t agent_ld(const uint32_t* p) {
  return __hip_atomic_load(p, __ATOMIC_RELAXED, __HIP_MEMORY_SCOPE_AGENT);
}

// =========================== cooperative fused path =========================
__global__ __launch_bounds__(1024, 1) void fused_k(
    const float* __restrict__ A, const float* __restrict__ B,
    float* __restrict__ out, uint32_t* __restrict__ ws,
    int nvec, int n, uint32_t j)
{
  __shared__ uint32_t smem[SMW];
  cg::grid_group grid = cg::this_grid();
  const int nblk = (int)gridDim.x;           // even, >=2 (host guarantees)
  const int nbm  = nblk >> 1;                // blocks per matrix
  const int blk  = (int)blockIdx.x;
  const int t    = (int)threadIdx.x;
  uint32_t* outu = (uint32_t*)out;
  const int m  = (blk >= nbm) ? 1 : 0;
  const int bb = blk - m * nbm;
  const int S  = nbm * TPB;

  // -------- phase 0: zero histograms + control words --------
  for (uint32_t i = (uint32_t)blk * TPB + t; i < 2u * NBINS; i += (uint32_t)nblk * TPB)
    outu[i] = 0u;
  if (blk == 0 && t < 64) ws[t] = 0u;
  __threadfence();
  grid.sync();

  // -------- phase 1: 65536-bin histogram of bits 30..15 (2x16-bit packed) ---
  {
    const float4* __restrict__ src = (const float4*)(m == 0 ? A : B);
    uint32_t* gh = outu + (uint32_t)m * NBINS;
    for (int i2 = t; i2 < 32768; i2 += TPB) smem[i2] = 0u;
    __syncthreads();
    for (int i = bb * TPB + t; i < nvec; i += S) {
      float4 f = src[i];
      const float v[4] = {f.x, f.y, f.z, f.w};
#pragma unroll
      for (int c = 0; c < 4; c++) {
        uint32_t u = __float_as_uint(v[c]) & 0x7fffffffu;
        uint32_t bin = u >> 15;
        atomicAdd(&smem[bin >> 1], 1u << ((bin & 1u) * 16u));
      }
    }
    __syncthreads();
    for (int w = t; w < 32768; w += TPB) {
      uint32_t x = smem[w];
      uint32_t c0 = x & 0xffffu, c1 = x >> 16;
      if (c0) atomicAdd(&gh[2 * w], c0);
      if (c1) atomicAdd(&gh[2 * w + 1], c1);
    }
  }
  __threadfence();
  grid.sync();

  // -------- phase 2: scan histogram -> P, rank (blocks 0,1) --------
  if (blk < 2) {
    const int mm = blk;
    const uint32_t* gh = outu + (uint32_t)mm * NBINS;
    uint32_t* bins = smem;                 // 64
    uint32_t* csum = smem + 32768;         // 1024
    uint32_t* ps   = smem + 33792;         // 1024
    const int w = t >> 6, l = t & 63;
    for (int k = 0; k < 64; k++) {
      uint32_t v = gh[(w << 12) + (k << 6) + l];   // coalesced 256B line
#pragma unroll
      for (int off = 32; off; off >>= 1) v += __shfl_xor(v, off, 64);
      if (l == 0) csum[(w << 6) + k] = v;
    }
    __syncthreads();
    ps[t] = csum[t];
    __syncthreads();
    for (int off = 1; off < 1024; off <<= 1) {
      uint32_t v = (t >= off) ? ps[t - off] : 0u;
      __syncthreads();
      ps[t] += v;
      __syncthreads();
    }
    uint32_t base = (t == 0) ? 0u : ps[t - 1];
    if (j >= base && j < base + csum[t]) { smem[34816] = (uint32_t)t; smem[34817] = j - base; }
    __syncthreads();
    const uint32_t chunk = smem[34816], rk = smem[34817];
    if (t < 64) bins[t] = gh[chunk * 64u + (uint32_t)t];
    __syncthreads();
    if (t < 64) {
      uint32_t lt = 0u;
      for (int k2 = 0; k2 < t; k2++) lt += bins[k2];
      if (rk >= lt && rk < lt + bins[t]) {
        ws[mm * 8] = chunk * 64u + (uint32_t)t;
        ws[mm * 8 + 1] = rk - lt;
      }
    }
  }
  __threadfence();
  grid.sync();

  // -------- phase 3: provisional mask + candidate collect --------
  {
    const float4* __restrict__ src = (const float4*)(m == 0 ? A : B);
    float4* __restrict__ dst = (float4*)(out + (size_t)m * (size_t)n);
    uint32_t* cand = outu + RBASE + (uint32_t)m * (CCAP * 2u);
    uint32_t* lbuf = smem;                 // [0, 2*LCAP) = [0,4096)
    const uint32_t P = agent_ld(&ws[m * 8]);
    if (t == 0) smem[34816] = 0u;          // ln
    __syncthreads();
    for (int i = bb * TPB + t; i < nvec; i += S) {
      float4 f = src[i];
      const float v[4] = {f.x, f.y, f.z, f.w};
      float r[4];
#pragma unroll
      for (int c = 0; c < 4; c++) {
        uint32_t u = __float_as_uint(v[c]) & 0x7fffffffu;
        uint32_t p = u >> 15;
        r[c] = (p > P) ? 1.0f : 0.0f;      // p==P fixed in phase 4
        if (p == P) {
          uint32_t s = atomicAdd(&smem[34816], 1u);   // LDS atomic
          if (s < LCAP) { lbuf[2u * s] = (uint32_t)i * 4u + (uint32_t)c; lbuf[2u * s + 1u] = u; }
        }
      }
      if (!(m == 1 && i >= (int)SKIP_F4))
        dst[i] = make_float4(r[0], r[1], r[2], r[3]);
    }
    __syncthreads();
    uint32_t c = smem[34816]; if (c > LCAP) c = LCAP;
    if (t == 0 && c) smem[34817] = atomicAdd(&ws[CNT(m)], c);  // ONE global atomic/block
    __syncthreads();
    if (c) {
      const uint32_t gb = smem[34817];
      for (uint32_t e = t; e < c; e += TPB) {
        uint32_t g = gb + e;
        if (g < CCAP) { cand[2u * g] = lbuf[2u * e]; cand[2u * g + 1u] = lbuf[2u * e + 1u]; }
      }
    }
  }
  __threadfence();
  grid.sync();

  // -------- phase 4: exact select + scatter fix (blocks 0,1) --------
  if (blk < 2) {
    const int mm = blk;
    uint32_t* W = ws + mm * 8;
    const uint32_t* cand = outu + RBASE + (uint32_t)mm * (CCAP * 2u);
    uint32_t* h   = smem;                  // 32768
    uint32_t* ps  = smem + 32768;          // 1024
    uint32_t* tie = smem + 33792;          // 1024
    uint32_t nc = agent_ld(&ws[CNT(mm)]); if (nc > CCAP) nc = CCAP;
    const uint32_t r = agent_ld(&W[1]);
    const uint32_t P = agent_ld(&W[0]);
    if (t == 0) { smem[34816] = 0u; smem[34817] = P << 15; smem[34818] = 0u; smem[34819] = 0u; }
    for (int i2 = t; i2 < 32768; i2 += TPB) h[i2] = 0u;
    __syncthreads();
    for (uint32_t e = t; e < nc; e += TPB)
      atomicAdd(&h[cand[2u * e + 1u] & 32767u], 1u);
    __syncthreads();
    uint32_t s = 0u;
    for (int k = 0; k < 32; k++) s += h[t * 32 + k];
    ps[t] = s;
    __syncthreads();
    for (int off = 1; off < 1024; off <<= 1) {
      uint32_t v = (t >= off) ? ps[t - off] : 0u;
      __syncthreads();
      ps[t] += v;
      __syncthreads();
    }
    uint32_t base = (t == 0) ? 0u : ps[t - 1];
    for (int k = 0; k < 32; k++) {
      uint32_t b2 = (uint32_t)t * 32u + (uint32_t)k;
      uint32_t c2 = h[b2];
      if (r >= base && r < base + c2) { smem[34817] = (P << 15) | b2; smem[34818] = r - base; }
      base += c2;
    }
    __syncthreads();
    const uint32_t T = smem[34817], target = smem[34818];
    for (uint32_t e = t; e < nc; e += TPB) {
      if (cand[2u * e + 1u] == T) {
        uint32_t slot = atomicAdd(&smem[34816], 1u);
        if (slot < 1024u) tie[slot] = cand[2u * e];
      }
    }
    __syncthreads();
    uint32_t E2 = smem[34816]; if (E2 > 1024u) E2 = 1024u;
    for (uint32_t c2 = t; c2 < E2; c2 += TPB) {
      uint32_t xi = tie[c2];
      uint32_t lt = 0u;
      for (uint32_t k2 = 0; k2 < E2; k2++) lt += (tie[k2] < xi) ? 1u : 0u;
      if (lt == target) smem[34819] = xi;  // target-th smallest tie index
    }
    __syncthreads();
    if (t == 0) { W[3] = T; W[4] = smem[34819]; }
    const uint32_t C = smem[34819];
    float* dstf = out + (size_t)mm * (size_t)n;
    for (uint32_t e = t; e < nc; e += TPB) {
      uint32_t idx = cand[2u * e];
      if (mm == 1 && idx >= SKIP_WORD) continue;   // phase 5 covers the tail
      uint32_t u = cand[2u * e + 1u];
      dstf[idx] = (u > T || (u == T && idx >= C)) ? 1.0f : 0.0f;
    }
  }
  __threadfence();
  grid.sync();

  // -------- phase 5: fill matrix-1 tail exactly --------
  {
    const uint32_t T = agent_ld(&ws[8 + 3]), C = agent_ld(&ws[8 + 4]);
    for (uint32_t tid = (uint32_t)blk * TPB + t; tid < RWORDS / 4u; tid += (uint32_t)nblk * TPB) {
      uint32_t i = SKIP_F4 + tid;
      float4 f = ((const float4*)B)[i];
      const float v[4] = {f.x, f.y, f.z, f.w};
      float r[4];
#pragma unroll
      for (int c = 0; c < 4; c++) {
        uint32_t u = __float_as_uint(v[c]) & 0x7fffffffu;
        uint32_t idx = i * 4u + (uint32_t)c;
        r[c] = (u > T || (u == T && idx >= C)) ? 1.0f : 0.0f;
      }
      ((float4*)(out + (size_t)n))[i] = make_float4(r[0], r[1], r[2], r[3]);
    }
  }
}

// =========================== fallback path (round-5, verified) ==============
#define FLCAP 256u

__global__ void init_k(uint32_t* __restrict__ ws, uint32_t* __restrict__ outbuf) {
  uint32_t i = blockIdx.x * blockDim.x + threadIdx.x;
  if (i < 2u * NBINS) outbuf[i] = 0u;
  if (i < 64u) ws[i] = 0u;
}

__global__ __launch_bounds__(1024, 1) void hist_k(const float* __restrict__ A,
                                                  const float* __restrict__ B,
                                                  uint32_t* __restrict__ outbuf,
                                                  int nvec) {
  const int m = blockIdx.y;
  const float4* __restrict__ src = (const float4*)(m == 0 ? A : B);
  uint32_t* gh = outbuf + (uint32_t)m * NBINS;
  __shared__ uint32_t h[NBINS / 2];
  for (int i = threadIdx.x; i < (int)(NBINS / 2); i += blockDim.x) h[i] = 0u;
  __syncthreads();
  int idx0 = blockIdx.x * blockDim.x + threadIdx.x;
  int stride = gridDim.x * blockDim.x;
  for (int i = idx0; i < nvec; i += stride) {
    float4 f = src[i];
    const float v[4] = {f.x, f.y, f.z, f.w};
#pragma unroll
    for (int c = 0; c < 4; c++) {
      uint32_t u = __float_as_uint(v[c]) & 0x7fffffffu;
      uint32_t b = u >> 15;
      atomicAdd(&h[b >> 1], 1u << ((b & 1u) * 16u));
    }
  }
  __syncthreads();
  for (int w = threadIdx.x; w < (int)(NBINS / 2); w += blockDim.x) {
    uint32_t x = h[w];
    uint32_t c0 = x & 0xffffu, c1 = x >> 16;
    if (c0) atomicAdd(&gh[2 * w], c0);
    if (c1) atomicAdd(&gh[2 * w + 1], c1);
  }
}

__global__ __launch_bounds__(1024, 1) void scan16_k(const uint32_t* __restrict__ outbuf,
                                                    uint32_t* __restrict__ ws, uint32_t j) {
  const int m = blockIdx.x;
  const uint32_t* gh = outbuf + (uint32_t)m * NBINS;
  uint32_t* W = ws + m * 8;
  __shared__ uint32_t csum[1024];
  __shared__ uint32_t ps[1024];
  __shared__ uint32_t sChunk, sRank;
  __shared__ uint32_t bins[64];
  const int t = threadIdx.x;
  const int w = t >> 6, l = t & 63;
  for (int k = 0; k < 64; k++) {
    uint32_t v = gh[(w << 12) + (k << 6) + l];
#pragma unroll
    for (int off = 32; off; off >>= 1) v += __shfl_xor(v, off, 64);
    if (l == 0) csum[(w << 6) + k] = v;
  }
  __syncthreads();
  ps[t] = csum[t];
  __syncthreads();
  for (int off = 1; off < 1024; off <<= 1) {
    uint32_t v = (t >= off) ? ps[t - off] : 0u;
    __syncthreads();
    ps[t] += v;
    __syncthreads();
  }
  uint32_t base = (t == 0) ? 0u : ps[t - 1];
  if (j >= base && j < base + csum[t]) { sChunk = (uint32_t)t; sRank = j - base; }
  __syncthreads();
  const uint32_t chunk = sChunk, rk = sRank;
  if (t < 64) bins[t] = gh[chunk * 64u + (uint32_t)t];
  __syncthreads();
  if (t < 64) {
    uint32_t lt = 0u;
    for (int k2 = 0; k2 < t; k2++) lt += bins[k2];
    if (rk >= lt && rk < lt + bins[t]) { W[0] = chunk * 64u + (uint32_t)t; W[1] = rk - lt; }
  }
}

__global__ void mask_collect_k(const float* __restrict__ A, const float* __restrict__ B,
                               float* __restrict__ out, uint32_t* __restrict__ ws,
                               uint32_t* __restrict__ outbuf, int nvec, int n) {
  const int m = blockIdx.y;
  const float4* __restrict__ src = (const float4*)(m == 0 ? A : B);
  float4* __restrict__ dst = (float4*)(out + (size_t)m * (size_t)n);
  const uint32_t P = ws[m * 8];
  uint32_t* cand = outbuf + RBASE + (uint32_t)m * (CCAP * 2u);
  __shared__ uint32_t lbuf[2u * FLCAP];
  __shared__ uint32_t ln, lbase;
  if (threadIdx.x == 0) ln = 0u;
  __syncthreads();
  int idx0 = blockIdx.x * blockDim.x + threadIdx.x;
  int stride = gridDim.x * blockDim.x;
  for (int i = idx0; i < nvec; i += stride) {
    float4 f = src[i];
    const float v[4] = {f.x, f.y, f.z, f.w};
    float r[4];
#pragma unroll
    for (int c = 0; c < 4; c++) {
      uint32_t u = __float_as_uint(v[c]) & 0x7fffffffu;
      uint32_t p = u >> 15;
      r[c] = (p > P) ? 1.0f : 0.0f;
      if (p == P) {
        uint32_t s = atomicAdd(&ln, 1u);
        if (s < FLCAP) { lbuf[2u * s] = (uint32_t)i * 4u + (uint32_t)c; lbuf[2u * s + 1u] = u; }
      }
    }
    if (!(m == 1 && i >= (int)SKIP_F4))
      nt_store4(&dst[i], r[0], r[1], r[2], r[3]);
  }
  __syncthreads();
  uint32_t c = ln; if (c > FLCAP) c = FLCAP;
  if (threadIdx.x == 0 && c) lbase = atomicAdd(&ws[CNT(m)], c);
  __syncthreads();
  for (uint32_t t = threadIdx.x; t < c; t += blockDim.x) {
    uint32_t g = lbase + t;
    if (g < CCAP) { cand[2u * g] = lbuf[2u * t]; cand[2u * g + 1u] = lbuf[2u * t + 1u]; }
  }
}

__global__ __launch_bounds__(1024, 1) void select_fix_k(uint32_t* __restrict__ ws,
                                                        uint32_t* __restrict__ outbuf,
                                                        float* __restrict__ out, int n) {
  const int m = blockIdx.x;
  uint32_t* W = ws + m * 8;
  const uint32_t* cand = outbuf + RBASE + (uint32_t)m * (CCAP * 2u);
  __shared__ uint32_t h[32768];
  __shared__ uint32_t ps[1024];
  __shared__ uint32_t sT, sTarget, sC;
  __shared__ uint32_t tie_idx[1024];
  __shared__ uint32_t tie_n;
  const int t = threadIdx.x;
  uint32_t nc = ws[CNT(m)]; if (nc > CCAP) nc = CCAP;
  const uint32_t r = W[1];
  const uint32_t P = W[0];
  if (t == 0) { tie_n = 0u; sT = P << 15; sTarget = 0u; sC = 0u; }
  for (int i = t; i < 32768; i += 1024) h[i] = 0u;
  __syncthreads();
  for (uint32_t e = t; e < nc; e += 1024u)
    atomicAdd(&h[cand[2u * e + 1u] & 32767u], 1u);
  __syncthreads();
  uint32_t s = 0u;
  for (int k = 0; k < 32; k++) s += h[t * 32 + k];
  ps[t] = s;
  __syncthreads();
  for (int off = 1; off < 1024; off <<= 1) {
    uint32_t v = (t >= off) ? ps[t - off] : 0u;
    __syncthreads();
    ps[t] += v;
    __syncthreads();
  }
  uint32_t base = (t == 0) ? 0u : ps[t - 1];
  for (int k = 0; k < 32; k++) {
    uint32_t b = (uint32_t)t * 32u + (uint32_t)k;
    uint32_t c = h[b];
    if (r >= base && r < base + c) { sT = (P << 15) | b; sTarget = r - base; }
    base += c;
  }
  __syncthreads();
  const uint32_t T = sT, target = sTarget;
  for (uint32_t e = t; e < nc; e += 1024u) {
    if (cand[2u * e + 1u] == T) {
      uint32_t slot = atomicAdd(&tie_n, 1u);
      if (slot < 1024u) tie_idx[slot] = cand[2u * e];
    }
  }
  __syncthreads();
  uint32_t E2 = tie_n; if (E2 > 1024u) E2 = 1024u;
  for (uint32_t c2 = t; c2 < E2; c2 += 1024u) {
    uint32_t xi = tie_idx[c2];
    uint32_t lt = 0u;
    for (uint32_t k2 = 0; k2 < E2; k2++) lt += (tie_idx[k2] < xi) ? 1u : 0u;
    if (lt == target) sC = xi;
  }
  __syncthreads();
  if (t == 0) { W[3] = T; W[4] = sC; }
  const uint32_t C = sC;
  float* dstf = out + (size_t)m * (size_t)n;
  for (uint32_t e = t; e < nc; e += 1024u) {
    uint32_t idx = cand[2u * e];
    if (m == 1 && idx >= SKIP_WORD) continue;
    uint32_t u = cand[2u * e + 1u];
    dstf[idx] = (u > T || (u == T && idx >= C)) ? 1.0f : 0.0f;
  }
}

__global__ void fill_tail_k(const float* __restrict__ B, float* __restrict__ out,
                            const uint32_t* __restrict__ ws, int n) {
  const uint32_t* W = ws + 8;
  const uint32_t T = W[3], C = W[4];
  const float4* __restrict__ src = (const float4*)B;
  float4* __restrict__ dst = (float4*)(out + (size_t)n);
  uint32_t i = SKIP_F4 + blockIdx.x * blockDim.x + threadIdx.x;
  if (i < (uint32_t)(n / 4)) {
    float4 f = src[i];
    const float v[4] = {f.x, f.y, f.z, f.w};
    float r[4];
#pragma unroll
    for (int c = 0; c < 4; c++) {
      uint32_t u = __float_as_uint(v[c]) & 0x7fffffffu;
      uint32_t idx = i * 4u + (uint32_t)c;
      r[c] = (u > T || (u == T && idx >= C)) ? 1.0f : 0.0f;
    }
    nt_store4(&dst[i], r[0], r[1], r[2], r[3]);
  }
}

// ================================ launcher ==================================
extern "C" void kernel_launch(void* const* d_in, const int* in_sizes, int n_in,
                              void* d_out, int out_size, void* d_ws, size_t ws_size,
                              hipStream_t stream) {
  const float* A = (const float*)d_in[0];
  const float* B = (const float*)d_in[1];
  float* out = (float*)d_out;
  uint32_t* ws = (uint32_t*)d_ws;
  uint32_t* outbuf = (uint32_t*)d_out;
  int n = in_sizes[0];                                     // 16777216 per matrix
  int nvec = n / 4;
  uint32_t j = (uint32_t)((1.0 - 0.1) * (double)n);        // == Python int((1-k)*n)

  // Co-residency by construction (host-only queries; graph-capture safe).
  int perCU = 0, cus = 0, dev = 0;
  (void)hipGetDevice(&dev);
  (void)hipDeviceGetAttribute(&cus, hipDeviceAttributeMultiprocessorCount, dev);
  hipError_t occ_err = hipOccupancyMaxActiveBlocksPerMultiprocessor(
      &perCU, (const void*)fused_k, TPB, 0);
  int nblk = (occ_err == hipSuccess && perCU > 0 && cus > 0) ? perCU * cus : 0;
  if (nblk > 256) nblk = 256;
  nblk &= ~1;                                              // even split A/B

  hipError_t lerr = hipErrorUnknown;
  if (nblk >= 2) {
    void* args[] = {(void*)&A, (void*)&B, (void*)&out, (void*)&ws,
                    (void*)&nvec, (void*)&n, (void*)&j};
    lerr = hipLaunchCooperativeKernel((const void*)fused_k, dim3(nblk), dim3(TPB),
                                      args, 0, stream);
  }
  if (lerr != hipSuccess) {
    // Verified round-5 pipeline (413 us) as a correctness-preserving fallback.
    init_k<<<(2u * NBINS + 255) / 256, 256, 0, stream>>>(ws, outbuf);
    hist_k<<<dim3(128, 2), 1024, 0, stream>>>(A, B, outbuf, nvec);
    scan16_k<<<2, 1024, 0, stream>>>(outbuf, ws, j);
    mask_collect_k<<<dim3(4096, 2), 256, 0, stream>>>(A, B, out, ws, outbuf, nvec, n);
    select_fix_k<<<2, 1024, 0, stream>>>(ws, outbuf, out, n);
    fill_tail_k<<<(n / 4 - SKIP_F4 + 255) / 256, 256, 0, stream>>>(B, out, ws, n);
  }
}

// Round 9
// 380.334 us; speedup vs baseline: 2.0314x; 2.0314x over previous
//
#include <hip/hip_runtime.h>
#include <stdint.h>

// ---------------------------------------------------------------------------
// Exact top-k (k=10%) magnitude mask via 16-bit-prefix radix select.
// Six dispatches (round-5 verified structure + 8-deep load batching in the
// two full-scan kernels; NO inter-block spin/ordering constructs -- G16):
//   init -> hist -> scan16 -> mask_collect -> select_fix -> fill_tail
//
// d_out (33554432 u32 words) scratch layout:
//   [0, 131072)  : two 65536-bin histograms (zeroed by init, filled by hist,
//                  read by scan16, overwritten by matrix-0 mask)
//   [RBASE, end) : candidate (idx,u) pairs, CCAP per matrix (matrix-1 mask
//                  skips this tail; select_fix never writes there;
//                  fill_tail writes it exactly at the end)
// d_ws (64 u32): per matrix m at ws+8*m: [0]=P [1]=rank [3]=T [4]=C;
//   candidate counters ws[32]/ws[48] (own cache lines).
// ---------------------------------------------------------------------------

#define NBINS       65536u
#define CCAP        65536u
#define TOTAL_WORDS 33554432u
#define RWORDS      (2u * CCAP * 2u)                // 262144 words = 1 MiB
#define RBASE       (TOTAL_WORDS - RWORDS)          // 33292288
#define SKIP_WORD   (RBASE - 16777216u)             // 16515072
#define SKIP_F4     (SKIP_WORD / 4u)                // 4128768
#define CNT(m)      (32u + (uint32_t)(m) * 16u)
#define LCAP        256u

__global__ void init_k(uint32_t* __restrict__ ws, uint32_t* __restrict__ outbuf) {
  uint32_t i = blockIdx.x * blockDim.x + threadIdx.x;
  if (i < 2u * NBINS) outbuf[i] = 0u;
  if (i < 64u) ws[i] = 0u;
}

// PASS 1: full scan, 65536-bin histogram of bits 30..15.
// 128 KiB LDS (2x16-bit packed bins) -> 1 block/CU (50% occ). 8-deep float4
// load batching (8 KB/wave in flight) hides HBM latency at that occupancy;
// round-5's single-outstanding-load version was latency-bound (~90us est).
__global__ __launch_bounds__(1024, 1) void hist_k(const float* __restrict__ A,
                                                  const float* __restrict__ B,
                                                  uint32_t* __restrict__ outbuf,
                                                  int nvec) {
  const int m = blockIdx.y;
  const float4* __restrict__ src = (const float4*)(m == 0 ? A : B);
  uint32_t* gh = outbuf + (uint32_t)m * NBINS;
  __shared__ uint32_t h[NBINS / 2];
  for (int i = threadIdx.x; i < (int)(NBINS / 2); i += blockDim.x) h[i] = 0u;
  __syncthreads();
  const int i0 = blockIdx.x * blockDim.x + threadIdx.x;
  const int S = gridDim.x * blockDim.x;              // 131072; nvec = 32*S
  for (int base = i0; base < nvec; base += 8 * S) {
    float4 f[8];
#pragma unroll
    for (int q = 0; q < 8; q++) {
      int i = base + q * S;
      if (i < nvec) f[q] = src[i];
    }
#pragma unroll
    for (int q = 0; q < 8; q++) {
      int i = base + q * S;
      if (i >= nvec) break;
      const float v[4] = {f[q].x, f[q].y, f[q].z, f[q].w};
#pragma unroll
      for (int c = 0; c < 4; c++) {
        uint32_t u = __float_as_uint(v[c]) & 0x7fffffffu;
        uint32_t b = u >> 15;
        atomicAdd(&h[b >> 1], 1u << ((b & 1u) * 16u));
      }
    }
  }
  __syncthreads();
  for (int w = threadIdx.x; w < (int)(NBINS / 2); w += blockDim.x) {
    uint32_t x = h[w];
    uint32_t c0 = x & 0xffffu, c1 = x >> 16;
    if (c0) atomicAdd(&gh[2 * w], c0);
    if (c1) atomicAdd(&gh[2 * w + 1], c1);
  }
}

// Scan the 65536-bin histogram: find bin containing rank j -> P, rank-in-bin.
// Coalesced: each wave-iter reads 64 consecutive bins, shfl-reduces.
__global__ __launch_bounds__(1024, 1) void scan16_k(const uint32_t* __restrict__ outbuf,
                                                    uint32_t* __restrict__ ws, uint32_t j) {
  const int m = blockIdx.x;
  const uint32_t* gh = outbuf + (uint32_t)m * NBINS;
  uint32_t* W = ws + m * 8;
  __shared__ uint32_t csum[1024];
  __shared__ uint32_t ps[1024];
  __shared__ uint32_t sChunk, sRank;
  __shared__ uint32_t bins[64];
  const int t = threadIdx.x;
  const int w = t >> 6, l = t & 63;
  for (int k = 0; k < 64; k++) {
    uint32_t v = gh[(w << 12) + (k << 6) + l];
#pragma unroll
    for (int off = 32; off; off >>= 1) v += __shfl_xor(v, off, 64);
    if (l == 0) csum[(w << 6) + k] = v;
  }
  __syncthreads();
  ps[t] = csum[t];
  __syncthreads();
  for (int off = 1; off < 1024; off <<= 1) {
    uint32_t v = (t >= off) ? ps[t - off] : 0u;
    __syncthreads();
    ps[t] += v;
    __syncthreads();
  }
  uint32_t base = (t == 0) ? 0u : ps[t - 1];
  if (j >= base && j < base + csum[t]) { sChunk = (uint32_t)t; sRank = j - base; }
  __syncthreads();
  const uint32_t chunk = sChunk, rk = sRank;
  if (t < 64) bins[t] = gh[chunk * 64u + (uint32_t)t];
  __syncthreads();
  if (t < 64) {
    uint32_t lt = 0u;
    for (int k2 = 0; k2 < t; k2++) lt += bins[k2];
    if (rk >= lt && rk < lt + bins[t]) { W[0] = chunk * 64u + (uint32_t)t; W[1] = rk - lt; }
  }
}

// PASS 2 (fused with final mask): provisional mask by 16-bit prefix compare;
// candidates staged in LDS (cheap LDS atomics), flushed with ONE global
// atomicAdd per block. 8-deep load batching; 2048x2 x 256 covers nvec exactly.
__global__ void mask_collect_k(const float* __restrict__ A, const float* __restrict__ B,
                               float* __restrict__ out, uint32_t* __restrict__ ws,
                               uint32_t* __restrict__ outbuf, int nvec, int n) {
  const int m = blockIdx.y;
  const float4* __restrict__ src = (const float4*)(m == 0 ? A : B);
  float4* __restrict__ dst = (float4*)(out + (size_t)m * (size_t)n);
  const uint32_t P = ws[m * 8];
  uint32_t* cand = outbuf + RBASE + (uint32_t)m * (CCAP * 2u);
  __shared__ uint32_t lbuf[2u * LCAP];
  __shared__ uint32_t ln, lbase;
  if (threadIdx.x == 0) ln = 0u;
  __syncthreads();
  const int i0 = blockIdx.x * blockDim.x + threadIdx.x;
  const int S = gridDim.x * blockDim.x;              // 524288; nvec == 8*S
  float4 f[8];
#pragma unroll
  for (int q = 0; q < 8; q++) {
    int i = i0 + q * S;
    if (i < nvec) f[q] = src[i];
  }
#pragma unroll
  for (int q = 0; q < 8; q++) {
    int i = i0 + q * S;
    if (i >= nvec) break;
    const float v[4] = {f[q].x, f[q].y, f[q].z, f[q].w};
    float r[4];
#pragma unroll
    for (int c = 0; c < 4; c++) {
      uint32_t u = __float_as_uint(v[c]) & 0x7fffffffu;
      uint32_t p = u >> 15;
      r[c] = (p > P) ? 1.0f : 0.0f;          // p==P resolved by select_fix_k
      if (p == P) {
        uint32_t s = atomicAdd(&ln, 1u);     // LDS atomic: cheap, rare (~0.2%)
        if (s < LCAP) { lbuf[2u * s] = (uint32_t)i * 4u + (uint32_t)c; lbuf[2u * s + 1u] = u; }
      }
    }
    if (!(m == 1 && i >= (int)SKIP_F4))
      dst[i] = make_float4(r[0], r[1], r[2], r[3]);
  }
  __syncthreads();
  uint32_t c = ln; if (c > LCAP) c = LCAP;
  if (threadIdx.x == 0 && c) lbase = atomicAdd(&ws[CNT(m)], c);   // ONE global atomic/block
  __syncthreads();
  for (uint32_t t = threadIdx.x; t < c; t += blockDim.x) {
    uint32_t g = lbase + t;
    if (g < CCAP) { cand[2u * g] = lbuf[2u * t]; cand[2u * g + 1u] = lbuf[2u * t + 1u]; }
  }
}

// Exact select among candidates: 15 remaining bits -> 32768-bin LDS histogram
// gives the EXACT threshold T; selected bin IS the tie set. Resolve tie cutoff
// C, scatter-fix candidate entries. Never writes words >= RBASE.
__global__ __launch_bounds__(1024, 1) void select_fix_k(uint32_t* __restrict__ ws,
                                                        uint32_t* __restrict__ outbuf,
                                                        float* __restrict__ out, int n) {
  const int m = blockIdx.x;
  uint32_t* W = ws + m * 8;
  const uint32_t* cand = outbuf + RBASE + (uint32_t)m * (CCAP * 2u);
  __shared__ uint32_t h[32768];
  __shared__ uint32_t ps[1024];
  __shared__ uint32_t sT, sTarget, sC;
  __shared__ uint32_t tie_idx[1024];
  __shared__ uint32_t tie_n;
  const int t = threadIdx.x;
  uint32_t nc = ws[CNT(m)]; if (nc > CCAP) nc = CCAP;
  const uint32_t r = W[1];
  const uint32_t P = W[0];
  if (t == 0) { tie_n = 0u; sT = P << 15; sTarget = 0u; sC = 0u; }
  for (int i = t; i < 32768; i += 1024) h[i] = 0u;
  __syncthreads();
  for (uint32_t e = t; e < nc; e += 1024u)
    atomicAdd(&h[cand[2u * e + 1u] & 32767u], 1u);
  __syncthreads();
  uint32_t s = 0u;
  for (int k = 0; k < 32; k++) s += h[t * 32 + k];
  ps[t] = s;
  __syncthreads();
  for (int off = 1; off < 1024; off <<= 1) {
    uint32_t v = (t >= off) ? ps[t - off] : 0u;
    __syncthreads();
    ps[t] += v;
    __syncthreads();
  }
  uint32_t base = (t == 0) ? 0u : ps[t - 1];
  for (int k = 0; k < 32; k++) {
    uint32_t b = (uint32_t)t * 32u + (uint32_t)k;
    uint32_t c = h[b];
    if (r >= base && r < base + c) { sT = (P << 15) | b; sTarget = r - base; }
    base += c;
  }
  __syncthreads();
  const uint32_t T = sT, target = sTarget;
  for (uint32_t e = t; e < nc; e += 1024u) {
    if (cand[2u * e + 1u] == T) {
      uint32_t slot = atomicAdd(&tie_n, 1u);
      if (slot < 1024u) tie_idx[slot] = cand[2u * e];
    }
  }
  __syncthreads();
  uint32_t E2 = tie_n; if (E2 > 1024u) E2 = 1024u;
  for (uint32_t c2 = t; c2 < E2; c2 += 1024u) {
    uint32_t xi = tie_idx[c2];
    uint32_t lt = 0u;
    for (uint32_t k2 = 0; k2 < E2; k2++) lt += (tie_idx[k2] < xi) ? 1u : 0u;
    if (lt == target) sC = xi;               // target-th smallest tie index
  }
  __syncthreads();
  if (t == 0) { W[3] = T; W[4] = sC; }
  const uint32_t C = sC;
  float* dstf = out + (size_t)m * (size_t)n;
  for (uint32_t e = t; e < nc; e += 1024u) {
    uint32_t idx = cand[2u * e];
    if (m == 1 && idx >= SKIP_WORD) continue;   // covered by fill_tail_k
    uint32_t u = cand[2u * e + 1u];
    dstf[idx] = (u > T || (u == T && idx >= C)) ? 1.0f : 0.0f;
  }
}

// Fill the tail region of matrix-1's output with the exact rule.
__global__ void fill_tail_k(const float* __restrict__ B, float* __restrict__ out,
                            const uint32_t* __restrict__ ws, int n) {
  const uint32_t* W = ws + 8;
  const uint32_t T = W[3], C = W[4];
  const float4* __restrict__ src = (const float4*)B;
  float4* __restrict__ dst = (float4*)(out + (size_t)n);
  uint32_t i = SKIP_F4 + blockIdx.x * blockDim.x + threadIdx.x;
  if (i < (uint32_t)(n / 4)) {
    float4 f = src[i];
    const float v[4] = {f.x, f.y, f.z, f.w};
    float r[4];
#pragma unroll
    for (int c = 0; c < 4; c++) {
      uint32_t u = __float_as_uint(v[c]) & 0x7fffffffu;
      uint32_t idx = i * 4u + (uint32_t)c;
      r[c] = (u > T || (u == T && idx >= C)) ? 1.0f : 0.0f;
    }
    dst[i] = make_float4(r[0], r[1], r[2], r[3]);
  }
}

extern "C" void kernel_launch(void* const* d_in, const int* in_sizes, int n_in,
                              void* d_out, int out_size, void* d_ws, size_t ws_size,
                              hipStream_t stream) {
  const float* A = (const float*)d_in[0];
  const float* B = (const float*)d_in[1];
  float* out = (float*)d_out;
  uint32_t* ws = (uint32_t*)d_ws;
  uint32_t* outbuf = (uint32_t*)d_out;
  const int n = in_sizes[0];                               // 16777216 per matrix
  const int nvec = n / 4;
  const uint32_t j = (uint32_t)((1.0 - 0.1) * (double)n);  // == Python int((1-k)*n)

  init_k<<<(2u * NBINS + 255) / 256, 256, 0, stream>>>(ws, outbuf);
  hist_k<<<dim3(128, 2), 1024, 0, stream>>>(A, B, outbuf, nvec);
  scan16_k<<<2, 1024, 0, stream>>>(outbuf, ws, j);
  mask_collect_k<<<dim3(2048, 2), 256, 0, stream>>>(A, B, out, ws, outbuf, nvec, n);
  select_fix_k<<<2, 1024, 0, stream>>>(ws, outbuf, out, n);
  fill_tail_k<<<(n / 4 - SKIP_F4 + 255) / 256, 256, 0, stream>>>(B, out, ws, n);
}

// Round 10
// 370.145 us; speedup vs baseline: 2.0873x; 1.0275x over previous
//
#include <hip/hip_runtime.h>
#include <stdint.h>

// ---------------------------------------------------------------------------
// Exact top-k (k=10%) magnitude mask via 16-bit-prefix radix select.
// Six dispatches (round-9 verified structure; mask_collect retuned):
//   init -> hist -> scan16 -> mask_collect -> select_fix -> fill_tail
//
// d_out (33554432 u32 words) scratch layout:
//   [0, 131072)  : two 65536-bin histograms (zeroed by init, filled by hist,
//                  read by scan16, overwritten by matrix-0 mask)
//   [RBASE, end) : candidate (idx,u) pairs, CCAP per matrix (matrix-1 mask
//                  skips this tail; select_fix never writes there;
//                  fill_tail writes it exactly at the end)
// d_ws (64 u32): per matrix m at ws+8*m: [0]=P [1]=rank [3]=T [4]=C;
//   candidate counters ws[32]/ws[48] (own cache lines).
//
// Known harness floor (R9 profile): 2x fillBufferAligned re-poison dispatches
// ~80us each per iteration -- not controllable from kernel code.
// ---------------------------------------------------------------------------

#define NBINS       65536u
#define CCAP        65536u
#define TOTAL_WORDS 33554432u
#define RWORDS      (2u * CCAP * 2u)                // 262144 words = 1 MiB
#define RBASE       (TOTAL_WORDS - RWORDS)          // 33292288
#define SKIP_WORD   (RBASE - 16777216u)             // 16515072
#define SKIP_F4     (SKIP_WORD / 4u)                // 4128768
#define CNT(m)      (32u + (uint32_t)(m) * 16u)
#define LCAP        256u

typedef float floatx4 __attribute__((ext_vector_type(4)));
__device__ __forceinline__ floatx4 nt_load4(const float4* p) {
  return __builtin_nontemporal_load(reinterpret_cast<const floatx4*>(p));
}

__global__ void init_k(uint32_t* __restrict__ ws, uint32_t* __restrict__ outbuf) {
  uint32_t i = blockIdx.x * blockDim.x + threadIdx.x;
  if (i < 2u * NBINS) outbuf[i] = 0u;
  if (i < 64u) ws[i] = 0u;
}

// PASS 1: full scan, 65536-bin histogram of bits 30..15.
// 128 KiB LDS (2x16-bit packed bins) -> 1 block/CU. 8-deep float4 batching
// (8 KB/wave in flight) hides HBM latency at 50% occupancy. Regular loads on
// purpose: they warm L3 for mask_collect's re-read.
__global__ __launch_bounds__(1024, 1) void hist_k(const float* __restrict__ A,
                                                  const float* __restrict__ B,
                                                  uint32_t* __restrict__ outbuf,
                                                  int nvec) {
  const int m = blockIdx.y;
  const float4* __restrict__ src = (const float4*)(m == 0 ? A : B);
  uint32_t* gh = outbuf + (uint32_t)m * NBINS;
  __shared__ uint32_t h[NBINS / 2];
  for (int i = threadIdx.x; i < (int)(NBINS / 2); i += blockDim.x) h[i] = 0u;
  __syncthreads();
  const int i0 = blockIdx.x * blockDim.x + threadIdx.x;
  const int S = gridDim.x * blockDim.x;              // 131072; nvec = 32*S
  for (int base = i0; base < nvec; base += 8 * S) {
    float4 f[8];
#pragma unroll
    for (int q = 0; q < 8; q++) {
      int i = base + q * S;
      if (i < nvec) f[q] = src[i];
    }
#pragma unroll
    for (int q = 0; q < 8; q++) {
      int i = base + q * S;
      if (i >= nvec) break;
      const float v[4] = {f[q].x, f[q].y, f[q].z, f[q].w};
#pragma unroll
      for (int c = 0; c < 4; c++) {
        uint32_t u = __float_as_uint(v[c]) & 0x7fffffffu;
        uint32_t b = u >> 15;
        atomicAdd(&h[b >> 1], 1u << ((b & 1u) * 16u));
      }
    }
  }
  __syncthreads();
  for (int w = threadIdx.x; w < (int)(NBINS / 2); w += blockDim.x) {
    uint32_t x = h[w];
    uint32_t c0 = x & 0xffffu, c1 = x >> 16;
    if (c0) atomicAdd(&gh[2 * w], c0);
    if (c1) atomicAdd(&gh[2 * w + 1], c1);
  }
}

// Scan the 65536-bin histogram: find bin containing rank j -> P, rank-in-bin.
__global__ __launch_bounds__(1024, 1) void scan16_k(const uint32_t* __restrict__ outbuf,
                                                    uint32_t* __restrict__ ws, uint32_t j) {
  const int m = blockIdx.x;
  const uint32_t* gh = outbuf + (uint32_t)m * NBINS;
  uint32_t* W = ws + m * 8;
  __shared__ uint32_t csum[1024];
  __shared__ uint32_t ps[1024];
  __shared__ uint32_t sChunk, sRank;
  __shared__ uint32_t bins[64];
  const int t = threadIdx.x;
  const int w = t >> 6, l = t & 63;
  for (int k = 0; k < 64; k++) {
    uint32_t v = gh[(w << 12) + (k << 6) + l];       // coalesced 256B line
#pragma unroll
    for (int off = 32; off; off >>= 1) v += __shfl_xor(v, off, 64);
    if (l == 0) csum[(w << 6) + k] = v;
  }
  __syncthreads();
  ps[t] = csum[t];
  __syncthreads();
  for (int off = 1; off < 1024; off <<= 1) {
    uint32_t v = (t >= off) ? ps[t - off] : 0u;
    __syncthreads();
    ps[t] += v;
    __syncthreads();
  }
  uint32_t base = (t == 0) ? 0u : ps[t - 1];
  if (j >= base && j < base + csum[t]) { sChunk = (uint32_t)t; sRank = j - base; }
  __syncthreads();
  const uint32_t chunk = sChunk, rk = sRank;
  if (t < 64) bins[t] = gh[chunk * 64u + (uint32_t)t];
  __syncthreads();
  if (t < 64) {
    uint32_t lt = 0u;
    for (int k2 = 0; k2 < t; k2++) lt += bins[k2];
    if (rk >= lt && rk < lt + bins[t]) { W[0] = chunk * 64u + (uint32_t)t; W[1] = rk - lt; }
  }
}

// PASS 2 (fused with final mask): provisional mask by 16-bit prefix compare;
// candidates staged in LDS, ONE global atomicAdd per block. 1024 threads x
// 512x2 blocks x 8-deep = exact coverage (no guards). NT loads: inputs are
// dead after this pass; evict-first hint leaves more L3 for the write stream.
__global__ __launch_bounds__(1024) void mask_collect_k(
    const float* __restrict__ A, const float* __restrict__ B,
    float* __restrict__ out, uint32_t* __restrict__ ws,
    uint32_t* __restrict__ outbuf, int nvec, int n) {
  const int m = blockIdx.y;
  const float4* __restrict__ src = (const float4*)(m == 0 ? A : B);
  float4* __restrict__ dst = (float4*)(out + (size_t)m * (size_t)n);
  const uint32_t P = ws[m * 8];
  uint32_t* cand = outbuf + RBASE + (uint32_t)m * (CCAP * 2u);
  __shared__ uint32_t lbuf[2u * LCAP];
  __shared__ uint32_t ln, lbase;
  if (threadIdx.x == 0) ln = 0u;
  __syncthreads();
  const int i0 = blockIdx.x * blockDim.x + threadIdx.x;
  const int S = gridDim.x * blockDim.x;              // 524288; nvec == 8*S exactly
  floatx4 f[8];
#pragma unroll
  for (int q = 0; q < 8; q++) f[q] = nt_load4(&src[i0 + q * S]);
#pragma unroll
  for (int q = 0; q < 8; q++) {
    const int i = i0 + q * S;
    const float v[4] = {f[q].x, f[q].y, f[q].z, f[q].w};
    float r[4];
#pragma unroll
    for (int c = 0; c < 4; c++) {
      uint32_t u = __float_as_uint(v[c]) & 0x7fffffffu;
      uint32_t p = u >> 15;
      r[c] = (p > P) ? 1.0f : 0.0f;          // p==P resolved by select_fix_k
      if (p == P) {
        uint32_t s = atomicAdd(&ln, 1u);     // LDS atomic: cheap, rare (~0.2%)
        if (s < LCAP) { lbuf[2u * s] = (uint32_t)i * 4u + (uint32_t)c; lbuf[2u * s + 1u] = u; }
      }
    }
    if (!(m == 1 && i >= (int)SKIP_F4))
      dst[i] = make_float4(r[0], r[1], r[2], r[3]);
  }
  __syncthreads();
  uint32_t c = ln; if (c > LCAP) c = LCAP;
  if (threadIdx.x == 0 && c) lbase = atomicAdd(&ws[CNT(m)], c);   // ONE global atomic/block
  __syncthreads();
  for (uint32_t t = threadIdx.x; t < c; t += blockDim.x) {
    uint32_t g = lbase + t;
    if (g < CCAP) { cand[2u * g] = lbuf[2u * t]; cand[2u * g + 1u] = lbuf[2u * t + 1u]; }
  }
}

// Exact select among candidates: 15 remaining bits -> 32768-bin LDS histogram
// gives the EXACT threshold T; selected bin IS the tie set. Resolve tie cutoff
// C, scatter-fix candidate entries. Never writes words >= RBASE.
__global__ __launch_bounds__(1024, 1) void select_fix_k(uint32_t* __restrict__ ws,
                                                        uint32_t* __restrict__ outbuf,
                                                        float* __restrict__ out, int n) {
  const int m = blockIdx.x;
  uint32_t* W = ws + m * 8;
  const uint32_t* cand = outbuf + RBASE + (uint32_t)m * (CCAP * 2u);
  __shared__ uint32_t h[32768];
  __shared__ uint32_t ps[1024];
  __shared__ uint32_t sT, sTarget, sC;
  __shared__ uint32_t tie_idx[1024];
  __shared__ uint32_t tie_n;
  const int t = threadIdx.x;
  uint32_t nc = ws[CNT(m)]; if (nc > CCAP) nc = CCAP;
  const uint32_t r = W[1];
  const uint32_t P = W[0];
  if (t == 0) { tie_n = 0u; sT = P << 15; sTarget = 0u; sC = 0u; }
  for (int i = t; i < 32768; i += 1024) h[i] = 0u;
  __syncthreads();
  for (uint32_t e = t; e < nc; e += 1024u)
    atomicAdd(&h[cand[2u * e + 1u] & 32767u], 1u);
  __syncthreads();
  uint32_t s = 0u;
  for (int k = 0; k < 32; k++) s += h[t * 32 + k];
  ps[t] = s;
  __syncthreads();
  for (int off = 1; off < 1024; off <<= 1) {
    uint32_t v = (t >= off) ? ps[t - off] : 0u;
    __syncthreads();
    ps[t] += v;
    __syncthreads();
  }
  uint32_t base = (t == 0) ? 0u : ps[t - 1];
  for (int k = 0; k < 32; k++) {
    uint32_t b = (uint32_t)t * 32u + (uint32_t)k;
    uint32_t c = h[b];
    if (r >= base && r < base + c) { sT = (P << 15) | b; sTarget = r - base; }
    base += c;
  }
  __syncthreads();
  const uint32_t T = sT, target = sTarget;
  for (uint32_t e = t; e < nc; e += 1024u) {
    if (cand[2u * e + 1u] == T) {
      uint32_t slot = atomicAdd(&tie_n, 1u);
      if (slot < 1024u) tie_idx[slot] = cand[2u * e];
    }
  }
  __syncthreads();
  uint32_t E2 = tie_n; if (E2 > 1024u) E2 = 1024u;
  for (uint32_t c2 = t; c2 < E2; c2 += 1024u) {
    uint32_t xi = tie_idx[c2];
    uint32_t lt = 0u;
    for (uint32_t k2 = 0; k2 < E2; k2++) lt += (tie_idx[k2] < xi) ? 1u : 0u;
    if (lt == target) sC = xi;               // target-th smallest tie index
  }
  __syncthreads();
  if (t == 0) { W[3] = T; W[4] = sC; }
  const uint32_t C = sC;
  float* dstf = out + (size_t)m * (size_t)n;
  for (uint32_t e = t; e < nc; e += 1024u) {
    uint32_t idx = cand[2u * e];
    if (m == 1 && idx >= SKIP_WORD) continue;   // covered by fill_tail_k
    uint32_t u = cand[2u * e + 1u];
    dstf[idx] = (u > T || (u == T && idx >= C)) ? 1.0f : 0.0f;
  }
}

// Fill the tail region of matrix-1's output with the exact rule.
__global__ void fill_tail_k(const float* __restrict__ B, float* __restrict__ out,
                            const uint32_t* __restrict__ ws, int n) {
  const uint32_t* W = ws + 8;
  const uint32_t T = W[3], C = W[4];
  const float4* __restrict__ src = (const float4*)B;
  float4* __restrict__ dst = (float4*)(out + (size_t)n);
  uint32_t i = SKIP_F4 + blockIdx.x * blockDim.x + threadIdx.x;
  if (i < (uint32_t)(n / 4)) {
    float4 f = src[i];
    const float v[4] = {f.x, f.y, f.z, f.w};
    float r[4];
#pragma unroll
    for (int c = 0; c < 4; c++) {
      uint32_t u = __float_as_uint(v[c]) & 0x7fffffffu;
      uint32_t idx = i * 4u + (uint32_t)c;
      r[c] = (u > T || (u == T && idx >= C)) ? 1.0f : 0.0f;
    }
    dst[i] = make_float4(r[0], r[1], r[2], r[3]);
  }
}

extern "C" void kernel_launch(void* const* d_in, const int* in_sizes, int n_in,
                              void* d_out, int out_size, void* d_ws, size_t ws_size,
                              hipStream_t stream) {
  const float* A = (const float*)d_in[0];
  const float* B = (const float*)d_in[1];
  float* out = (float*)d_out;
  uint32_t* ws = (uint32_t*)d_ws;
  uint32_t* outbuf = (uint32_t*)d_out;
  const int n = in_sizes[0];                               // 16777216 per matrix
  const int nvec = n / 4;
  const uint32_t j = (uint32_t)((1.0 - 0.1) * (double)n);  // == Python int((1-k)*n)

  init_k<<<(2u * NBINS + 255) / 256, 256, 0, stream>>>(ws, outbuf);
  hist_k<<<dim3(128, 2), 1024, 0, stream>>>(A, B, outbuf, nvec);
  scan16_k<<<2, 1024, 0, stream>>>(outbuf, ws, j);
  mask_collect_k<<<dim3(512, 2), 1024, 0, stream>>>(A, B, out, ws, outbuf, nvec, n);
  select_fix_k<<<2, 1024, 0, stream>>>(ws, outbuf, out, n);
  fill_tail_k<<<(n / 4 - SKIP_F4 + 255) / 256, 256, 0, stream>>>(B, out, ws, n);
}